// Round 9
// baseline (8683.731 us; speedup 1.0000x reference)
//
#include <hip/hip_runtime.h>
#include <hip/hip_fp16.h>

constexpr int kB = 128;
constexpr int kN = 1000;
constexpr int kE = 128;
constexpr int kH = 8;
constexpr float kFP8Scale = 64.f;         // fp8 values stored as v*64
constexpr float kQKScale = 0.25f / 64.f;  // 1/sqrt(16) folded with 1/64

typedef _Float16 h2 __attribute__((ext_vector_type(2)));
typedef float f2 __attribute__((ext_vector_type(2)));

__device__ __forceinline__ float fast_tanh(float x) {
  float t = __expf(2.f * x);
  return 1.f - 2.f / (t + 1.f);
}

__device__ __forceinline__ unsigned char enc_fp8(float v) {
  unsigned p = __builtin_amdgcn_cvt_pk_fp8_f32(v, v, 0, false);
  return (unsigned char)(p & 0xFF);
}

// packed fp8-pair dot: sacc += {fp8lo pair}*qa + {fp8hi pair}*qb  (v_pk_fma)
__device__ __forceinline__ void dotp(unsigned u, f2 qa, f2 qb, f2& sacc) {
  f2 lo = __builtin_amdgcn_cvt_pk_f32_fp8(u, false);
  f2 hi = __builtin_amdgcn_cvt_pk_f32_fp8(u, true);
  sacc += lo * qa;
  sacc += hi * qb;
}
// 16-elem fp8 dot (one uint4) against 16 f32 elems in q2[0..7] (f2 pairs).
__device__ __forceinline__ float dot16p(uint4 tq, const f2* q2) {
  f2 s = {0.f, 0.f};
  dotp(tq.x, q2[0], q2[1], s);
  dotp(tq.y, q2[2], q2[3], s);
  dotp(tq.z, q2[4], q2[5], s);
  dotp(tq.w, q2[6], q2[7], s);
  return s.x + s.y;
}
// packed V accumulate: a0 += hv2*{lo pair}; a1 += hv2*{hi pair}
__device__ __forceinline__ void vaccp(unsigned u, f2 hv2, f2& a0, f2& a1) {
  f2 lo = __builtin_amdgcn_cvt_pk_f32_fp8(u, false);
  f2 hi = __builtin_amdgcn_cvt_pk_f32_fp8(u, true);
  a0 += hv2 * lo;
  a1 += hv2 * hi;
}
// unpack 16 f16 (two uint4) -> 8 f2 of f32
__device__ __forceinline__ void unpack16(uint4 a, uint4 b, f2* q2) {
  unsigned w[8] = {a.x, a.y, a.z, a.w, b.x, b.y, b.z, b.w};
#pragma unroll
  for (int i = 0; i < 8; ++i) {
    h2 hh = __builtin_bit_cast(h2, w[i]);
    q2[i] = f2{(float)hh.x, (float)hh.y};
  }
}

// max+argmax combine; tie -> smaller node id (jnp.argmax semantics).
__device__ __forceinline__ void maxcomb(float& m, int& a, float mo, int ao) {
  bool take = (mo > m) || (mo == m && ao < a);
  m = take ? mo : m;
  a = take ? ao : a;
}

// ---- DPP cross-lane helpers (VALU pipe, not DS) ---------------------------
// 0xB1 = quad_perm xor1, 0x4E = quad_perm xor2, 0x141 = row_half_mirror
// (xor4-equiv within octet), 0x128 = row_ror:8 (xor8-equiv within 16 lanes).
template <int CTRL>
__device__ __forceinline__ float dpp_bcastf(float x) {
  return __builtin_bit_cast(
      float, __builtin_amdgcn_update_dpp(0, __builtin_bit_cast(int, x), CTRL,
                                         0xf, 0xf, true));
}
template <int CTRL>
__device__ __forceinline__ int dpp_bcasti(int x) {
  return __builtin_amdgcn_update_dpp(0, x, CTRL, 0xf, 0xf, true);
}
template <int CTRL>
__device__ __forceinline__ float dpp_addf(float x) {
  return x + dpp_bcastf<CTRL>(x);
}
template <int CTRL>
__device__ __forceinline__ void dpp_maxcomb(float& m, int& a) {
  float mo = dpp_bcastf<CTRL>(m);
  int ao = dpp_bcasti<CTRL>(a);
  maxcomb(m, a, mo, ao);
}

// LDS-only barrier: drains DS ops, leaves global register-loads in flight.
__device__ __forceinline__ void barrier_lds() {
  asm volatile("s_waitcnt lgkmcnt(0)" ::: "memory");
  __builtin_amdgcn_s_barrier();
  asm volatile("" ::: "memory");
}

// ---------------------------------------------------------------------------
// Kernel A: qkv projection -> fp8 (value*64) k / v / logit_k.
// ---------------------------------------------------------------------------
__global__ __launch_bounds__(384) void qkv_kernel(
    const float* __restrict__ ne, const float* __restrict__ Wqkv,
    const float* __restrict__ bqkv, unsigned char* __restrict__ kq,
    unsigned char* __restrict__ vq, unsigned char* __restrict__ lkq) {
  __shared__ float rows[16 * kE];
  int b = blockIdx.x;
  int n0 = blockIdx.y * 16;
  int ntile = min(16, kN - n0);
  int tid = threadIdx.x;

  for (int idx = tid; idx < ntile * kE; idx += 384)
    rows[idx] = ne[(b * kN + n0) * kE + idx];
  __syncthreads();

  int j = tid;  // 0..383
  float acc[16];
#pragma unroll
  for (int r = 0; r < 16; ++r) acc[r] = 0.f;
  for (int i = 0; i < kE; ++i) {
    float w = Wqkv[i * (3 * kE) + j];
#pragma unroll
    for (int r = 0; r < 16; ++r) acc[r] += rows[r * kE + i] * w;
  }
  float bias = bqkv[j];
  unsigned char* dst;
  int col;
  if (j < kE) { dst = kq; col = j; }
  else if (j < 2 * kE) { dst = vq; col = j - kE; }
  else { dst = lkq; col = j - 2 * kE; }
  for (int r = 0; r < ntile; ++r)
    dst[(size_t)(b * kN + n0 + r) * kE + col] =
        enc_fp8((acc[r] + bias) * kFP8Scale);
}

// ---------------------------------------------------------------------------
// Kernel B: qbase[b] = ge@Wfix + bfix + first@Wstep_top + bstep  (fp32)
// ---------------------------------------------------------------------------
__global__ __launch_bounds__(128) void qbase_kernel(
    const float* __restrict__ ne, const float* __restrict__ ge,
    const float* __restrict__ Wfix, const float* __restrict__ bfix,
    const float* __restrict__ Wstep, const float* __restrict__ bstep,
    float* __restrict__ qbase) {
  __shared__ float g[kE], f[kE];
  int b = blockIdx.x, e = threadIdx.x;
  g[e] = ge[b * kE + e];
  f[e] = ne[(size_t)b * kN * kE + e];  // node 0
  __syncthreads();
  float acc = bfix[e] + bstep[e];
  for (int i = 0; i < kE; ++i)
    acc += g[i] * Wfix[i * kE + e] + f[i] * Wstep[i * kE + e];
  qbase[b * kE + e] = acc;
}

// ---------------------------------------------------------------------------
// Kernel B2: qstep[b,n] = (qbase[b] + ne[b,n] @ Wbot) * kQKScale, f16.
// ---------------------------------------------------------------------------
__global__ __launch_bounds__(128) void qstep_kernel(
    const float* __restrict__ ne, const float* __restrict__ Wstep,
    const float* __restrict__ qbase, __half* __restrict__ qstep) {
  __shared__ float rows[8 * kE];
  int b = blockIdx.x;
  int n0 = blockIdx.y * 8;
  int tid = threadIdx.x;
  const float* Wbot = Wstep + kE * kE;

  for (int idx = tid; idx < 8 * kE; idx += 128)
    rows[idx] = ne[((size_t)b * kN + n0) * kE + idx];
  __syncthreads();

  float acc[8];
#pragma unroll
  for (int r = 0; r < 8; ++r) acc[r] = 0.f;
  for (int i = 0; i < kE; ++i) {
    float w = Wbot[i * kE + tid];
#pragma unroll
    for (int r = 0; r < 8; ++r) acc[r] += rows[r * kE + i] * w;
  }
  float qb = qbase[b * kE + tid];
#pragma unroll
  for (int r = 0; r < 8; ++r)
    qstep[((size_t)b * kN + n0 + r) * kE + tid] =
        __float2half((qb + acc[r]) * kQKScale);
}

// ---------------------------------------------------------------------------
// Kernel C: 999-step rollout, one 1024-thread block per batch element.
// Round-7 fused structure (head-alignment: p·V in registers) plus:
//  * packed v_pk_fma_f32 dot/acc paths (q/x unpacked to f32 pairs once/step)
//  * 4 barriers/step: B5 deleted — phase E pre-reads rem pairs for all 8
//    slots; phase F computes next-step jn via the local patch
//    (old<A ? old : old_next) in registers; phase A never reads rem, so
//    K/V gathers issue at the very top of the step.
//  * two-pass max-then-sum trees in E and F (2 exps/thread, short chains).
// ---------------------------------------------------------------------------
__global__ __launch_bounds__(1024) void rollout_kernel(
    const float* __restrict__ Wmlp, const float* __restrict__ bmlp,
    const unsigned char* __restrict__ kq, const unsigned char* __restrict__ vq,
    const unsigned char* __restrict__ lkq, const __half* __restrict__ qstep,
    float* __restrict__ out) {
  __shared__ __align__(16) int rem[1024];       // SORTED live ids (padded)
  __shared__ __align__(16) float parts[kE][65]; // ctx chunk partials, 33 KB
  __shared__ __align__(16) float wmT[kE][140];  // wmT[g][i]=Wmlp[i][g], 70 KB
  __shared__ float bm[kE];
  __shared__ __align__(16) float ctx[kE];
  __shared__ __align__(16) __half xh[kE];
  __shared__ float redSum[16][kH];
  __shared__ __align__(16) float4 redPack[16];  // (m, ssum, argbits, -)

  int b = blockIdx.x;
  int tid = threadIdx.x;
  int lane = tid & 63;
  int wave = tid >> 6;
  int g = tid >> 3;  // node-group 0..127; slots j = g + 128r
  int t = tid & 7;   // head / uint4 chunk within row

  const unsigned char* kqb = kq + (size_t)b * kN * kE;
  const unsigned char* vqb = vq + (size_t)b * kN * kE;
  const unsigned char* lqb = lkq + (size_t)b * kN * kE;
  const __half* qsb = qstep + (size_t)b * kN * kE;

  // stage Wmlp transposed into LDS (one-time; coalesced reads)
#pragma unroll
  for (int m = 0; m < 16; ++m) {
    int idx = tid * 16 + m;  // 0..16383
    wmT[idx & 127][idx >> 7] = Wmlp[idx];
  }
  // init sorted live list (padded with valid ids for safe speculative reads)
  rem[tid] = (tid < kN - 1) ? tid + 1 : kN - 1;
  if (tid < kE) bm[tid] = bmlp[tid];

  // current action + its q row (prefetched into registers; node 0 first)
  int A = 0;
  uint4 qa, qb_;
  {
    const uint4* qr = (const uint4*)qsb;
    qa = qr[2 * t];
    qb_ = qr[2 * t + 1];
  }
  float total = 0.f;

  // step-0 jn (initial rem[j] = j+1), register resident
  int jn[8];
#pragma unroll
  for (int r = 0; r < 8; ++r) {
    int j = g + 128 * r;
    jn[r] = (j < kN - 1) ? j + 1 : -1;
  }

  barrier_lds();  // init visible

  for (int step = 0; step < kN - 1; ++step) {
    int R = kN - 1 - step;  // live count (deterministic)

    // ========== phase A: fused scores + ctx accumulation =================
    // K/V loads issue immediately (jn is register-resident, no rem reads)
    uint4 kb0, vb0, kb1, vb1;
    if (jn[0] >= 0) {
      kb0 = ((const uint4*)(kqb + (size_t)jn[0] * kE))[t];
      vb0 = ((const uint4*)(vqb + (size_t)jn[0] * kE))[t];
    }
    if (jn[1] >= 0) {
      kb1 = ((const uint4*)(kqb + (size_t)jn[1] * kE))[t];
      vb1 = ((const uint4*)(vqb + (size_t)jn[1] * kE))[t];
    }
    f2 q2[8];
    unpack16(qa, qb_, q2);  // 16 cvt, once per step
    f2 acc2[8];             // ctx accum as f32 pairs (elems 4c..4c+3 per c)
#pragma unroll
    for (int i = 0; i < 8; ++i) acc2[i] = f2{0.f, 0.f};
    float den = 0.f;
#pragma unroll
    for (int r = 0; r < 8; ++r) {
      if (jn[r] < 0) break;  // sorted rem: deadness is monotone in r
      uint4 kk = (r & 1) ? kb1 : kb0;
      uint4 vv = (r & 1) ? vb1 : vb0;
      if (r + 2 < 8 && jn[r + 2] >= 0) {  // depth-2 slot pipeline
        if (r & 1) {
          kb1 = ((const uint4*)(kqb + (size_t)jn[r + 2] * kE))[t];
          vb1 = ((const uint4*)(vqb + (size_t)jn[r + 2] * kE))[t];
        } else {
          kb0 = ((const uint4*)(kqb + (size_t)jn[r + 2] * kE))[t];
          vb0 = ((const uint4*)(vqb + (size_t)jn[r + 2] * kE))[t];
        }
      }
      float s = dot16p(kk, q2);
      float hv = __expf(s);  // full head-t score (d=16): scores tiny
      den += hv;
      f2 hv2 = {hv, hv};
      vaccp(vv.x, hv2, acc2[0], acc2[1]);
      vaccp(vv.y, hv2, acc2[2], acc2[3]);
      vaccp(vv.z, hv2, acc2[4], acc2[5]);
      vaccp(vv.w, hv2, acc2[6], acc2[7]);
    }
    // lu prefetch (long cover: rest of A + B1 + C + D)
    uint4 lu[8];
#pragma unroll
    for (int r = 0; r < 8; ++r)
      if (jn[r] >= 0) lu[r] = ((const uint4*)(lqb + (size_t)jn[r] * kE))[t];
    // den: reduce over the 8 g-groups of this wave (preserve t = lane%8)
    den = dpp_addf<0x128>(den);
    den += __shfl_xor(den, 16);
    den += __shfl_xor(den, 32);
    if (lane < kH) redSum[wave][lane] = den;  // lane==t for lanes 0..7
    // acc: unpack to scalars, gw-pair fold (VALU), write 64-chunk parts
    {
      float av[16];
#pragma unroll
      for (int c = 0; c < 4; ++c) {
        av[4 * c + 0] = acc2[2 * c].x;
        av[4 * c + 1] = acc2[2 * c].y;
        av[4 * c + 2] = acc2[2 * c + 1].x;
        av[4 * c + 3] = acc2[2 * c + 1].y;
      }
#pragma unroll
      for (int i = 0; i < 16; ++i) av[i] = dpp_addf<0x128>(av[i]);
      if (((lane >> 3) & 1) == 0) {
        int chunk = wave * 4 + (lane >> 4);  // 0..63
#pragma unroll
        for (int i = 0; i < 16; ++i)
          parts[t * 16 + i][(chunk + 4 * t) & 63] = av[i];  // bank-injective
      }
    }
    barrier_lds();  // B1: parts, redSum ready

    // ========== phase C: finalize ctx (all threads, DPP octet tree) ======
    {
      int e = tid >> 3, k = tid & 7, hh = e >> 4;
      float s = 0.f;
#pragma unroll
      for (int m = 0; m < 8; ++m)
        s += parts[e][((8 * k + m) + 4 * hh) & 63];
      float d = redSum[2 * k][hh] + redSum[2 * k + 1][hh];
      s = dpp_addf<0xB1>(s);
      s = dpp_addf<0x4E>(s);
      s = dpp_addf<0x141>(s);
      d = dpp_addf<0xB1>(d);
      d = dpp_addf<0x4E>(d);
      d = dpp_addf<0x141>(d);
      if (k == 0) ctx[e] = s / (d * kFP8Scale);
    }
    barrier_lds();  // B2: ctx ready

    // ========== phase D: x = (bm + ctx @ Wmlp) * kQKScale (wm from LDS) ==
    {
      float xacc = 0.f;
      const float4* c4 = (const float4*)(ctx + t * 16);
      const float4* w4 = (const float4*)(&wmT[g][t * 16]);
#pragma unroll
      for (int k4 = 0; k4 < 4; ++k4) {
        float4 cv = c4[k4];
        float4 wv = w4[k4];
        xacc += cv.x * wv.x + cv.y * wv.y + cv.z * wv.z + cv.w * wv.w;
      }
      xacc = dpp_addf<0xB1>(xacc);
      xacc = dpp_addf<0x4E>(xacc);
      xacc = dpp_addf<0x141>(xacc);
      if (t == 0) xh[g] = __float2half((bm[g] + xacc) * kQKScale);
    }
    barrier_lds();  // B3: xh ready

    // ========== phase E: logits (lu in registers) + rem pre-reads ========
    // rem reads for shift-remove AND next-step jn patch happen HERE
    // (pre-B4); B4 fences them from the phase-F writes.
    int myv = rem[tid];
    int nxt = rem[(tid < 1023) ? tid + 1 : 1023];
    int pra[8], prb[8];
#pragma unroll
    for (int r = 0; r < 8; ++r) {
      int j = g + 128 * r;  // <= 1023
      pra[r] = rem[j];
      prb[r] = rem[(j < 1023) ? j + 1 : 1023];
    }
    float m0 = -1e30f;
    int arg = 0x7fffffff;
    {
      f2 x2[8];
      uint4 xv0 = ((const uint4*)xh)[2 * t];
      uint4 xv1 = ((const uint4*)xh)[2 * t + 1];
      unpack16(xv0, xv1, x2);
#pragma unroll
      for (int r = 0; r < 8; ++r)
        if (jn[r] >= 0) {  // uniform within each octet (depends on g only)
          float s = dot16p(lu[r], x2);
          s = dpp_addf<0xB1>(s);
          s = dpp_addf<0x4E>(s);
          s = dpp_addf<0x141>(s);
          if (t == r) {  // lane t captures entry r
            m0 = fast_tanh(s) * 10.f;
            arg = jn[r];
          }
        }
    }
    // two-pass wave reduction: (1) max+arg butterfly (no exp), (2) one exp
    // per lane + add butterfly.
    float M = m0;
    int argM = arg;
    dpp_maxcomb<0xB1>(M, argM);
    dpp_maxcomb<0x4E>(M, argM);
    dpp_maxcomb<0x141>(M, argM);
    dpp_maxcomb<0x128>(M, argM);
#pragma unroll
    for (int off = 16; off <= 32; off <<= 1) {
      float mo = __shfl_xor(M, off);
      int ao = __shfl_xor(argM, off);
      maxcomb(M, argM, mo, ao);
    }
    float ex = __expf(m0 - M);  // dead lanes: exp(-huge) = 0
    ex = dpp_addf<0xB1>(ex);
    ex = dpp_addf<0x4E>(ex);
    ex = dpp_addf<0x141>(ex);
    ex = dpp_addf<0x128>(ex);
    ex += __shfl_xor(ex, 16);
    ex += __shfl_xor(ex, 32);
    if (lane == 0)
      redPack[wave] = make_float4(M, ex, __int_as_float(argM), 0.f);
    barrier_lds();  // B4: reductions ready; rem reads fenced from writes

    // ====== phase F: final two-pass combine, q prefetch, jn patch ========
    {
      float4 rp = redPack[lane & 15];
      float mw = rp.x, sw = rp.y;
      int aw = __float_as_int(rp.z);
      float Mf = mw;
      int Af = aw;
      dpp_maxcomb<0xB1>(Mf, Af);
      dpp_maxcomb<0x4E>(Mf, Af);
      dpp_maxcomb<0x141>(Mf, Af);
      dpp_maxcomb<0x128>(Mf, Af);
      float sc = sw * __expf(mw - Mf);  // dead waves contribute 0
      sc = dpp_addf<0xB1>(sc);
      sc = dpp_addf<0x4E>(sc);
      sc = dpp_addf<0x141>(sc);
      sc = dpp_addf<0x128>(sc);
      A = Af;
      total += -logf(sc);  // chosen logit == M => log_p[act] = -log S
      // prefetch next q row (every thread knows A; no barrier until B1')
      const uint4* qr = (const uint4*)(qsb + (size_t)A * kE);
      qa = qr[2 * t];
      qb_ = qr[2 * t + 1];
      // next-step jn via locally patched sorted rem:
      // next[j] = old[j] < A ? old[j] : old[j+1]  (shift-left semantics)
      int Rn = R - 1;
#pragma unroll
      for (int r = 0; r < 8; ++r) {
        int j = g + 128 * r;
        jn[r] = (j < Rn) ? ((pra[r] < A) ? pra[r] : prb[r]) : -1;
      }
      // publish shift-remove for future steps (read again only in E',
      // which is fenced by B1'/B2'/B3')
      if (tid < R - 1 && myv >= A) rem[tid] = nxt;
    }
    // no end-of-step barrier: rem is next read in phase E' (3 barriers away)
  }
  if (tid == 0) out[b] = total;
}

// ---------------------------------------------------------------------------
extern "C" void kernel_launch(void* const* d_in, const int* in_sizes, int n_in,
                              void* d_out, int out_size, void* d_ws,
                              size_t ws_size, hipStream_t stream) {
  const float* ne = (const float*)d_in[0];
  const float* ge = (const float*)d_in[1];
  const float* Wqkv = (const float*)d_in[2];
  const float* bqkv = (const float*)d_in[3];
  const float* Wfix = (const float*)d_in[4];
  const float* bfix = (const float*)d_in[5];
  const float* Wstep = (const float*)d_in[6];
  const float* bstep = (const float*)d_in[7];
  const float* Wmlp = (const float*)d_in[8];
  const float* bmlp = (const float*)d_in[9];
  float* out = (float*)d_out;

  size_t nkv = (size_t)kB * kN * kE;  // bytes per fp8 tensor
  unsigned char* kq = (unsigned char*)d_ws;
  unsigned char* vq = kq + nkv;
  unsigned char* lkq = vq + nkv;
  __half* qstep = (__half*)(lkq + nkv);  // 2*nkv bytes
  float* qbase = (float*)(qstep + nkv);  // 64 KB

  qkv_kernel<<<dim3(kB, (kN + 15) / 16), 384, 0, stream>>>(ne, Wqkv, bqkv, kq,
                                                           vq, lkq);
  qbase_kernel<<<kB, kE, 0, stream>>>(ne, ge, Wfix, bfix, Wstep, bstep, qbase);
  qstep_kernel<<<dim3(kB, kN / 8), 128, 0, stream>>>(ne, Wstep, qbase, qstep);
  rollout_kernel<<<kB, 1024, 0, stream>>>(Wmlp, bmlp, kq, vq, lkq, qstep, out);
}